// Round 1
// baseline (1254.703 us; speedup 1.0000x reference)
//
#include <hip/hip_runtime.h>
#include <hip/hip_bf16.h>

#define T_TOK 4096
#define DM 1024
#define DF 2048
#define NE 8

typedef __attribute__((ext_vector_type(8))) short bf16x8;
typedef __attribute__((ext_vector_type(4))) float f32x4;

__device__ __forceinline__ unsigned short f2bf(float f) {
  union { float f; unsigned int i; } v; v.f = f;
  unsigned int r = v.i + 0x7fffu + ((v.i >> 16) & 1u);
  return (unsigned short)(r >> 16);
}

__device__ __forceinline__ uint4 pack8(float4 a, float4 b) {
  uint4 r;
  r.x = (unsigned int)f2bf(a.x) | ((unsigned int)f2bf(a.y) << 16);
  r.y = (unsigned int)f2bf(a.z) | ((unsigned int)f2bf(a.w) << 16);
  r.z = (unsigned int)f2bf(b.x) | ((unsigned int)f2bf(b.y) << 16);
  r.w = (unsigned int)f2bf(b.z) | ((unsigned int)f2bf(b.w) << 16);
  return r;
}

// ---------------- X fp32 -> bf16 ----------------
__global__ void cvt_x_kernel(const float* __restrict__ X, unsigned short* __restrict__ Xbf) {
  int idx = blockIdx.x * 256 + threadIdx.x;   // float4 index, total T_TOK*DM/4
  float4 v = ((const float4*)X)[idx];
  ushort4 o;
  o.x = f2bf(v.x); o.y = f2bf(v.y); o.z = f2bf(v.z); o.w = f2bf(v.w);
  ((ushort4*)Xbf)[idx] = o;
}

// ---------------- router: logits -> softmax -> top2 -> softmax(top2 probs) ----------------
__global__ void router_kernel(const float* __restrict__ X, const float* __restrict__ RW,
                              const float* __restrict__ bias, int* __restrict__ cnt,
                              int* __restrict__ lists, float* __restrict__ wpair) {
  int t = blockIdx.x * 4 + (threadIdx.x >> 6);   // one wave per token
  int lane = threadIdx.x & 63;
  float xv[16];
#pragma unroll
  for (int j = 0; j < 16; j++) xv[j] = X[(size_t)t * DM + lane + 64 * j];
  float logit[NE];
#pragma unroll
  for (int e = 0; e < NE; e++) {
    float s = 0.f;
#pragma unroll
    for (int j = 0; j < 16; j++) s += xv[j] * RW[e * DM + lane + 64 * j];
#pragma unroll
    for (int off = 32; off > 0; off >>= 1) s += __shfl_xor(s, off);
    logit[e] = s + bias[e];
  }
  if (lane == 0) {
    float mx = logit[0];
#pragma unroll
    for (int e = 1; e < NE; e++) mx = fmaxf(mx, logit[e]);
    float p[NE]; float sum = 0.f;
#pragma unroll
    for (int e = 0; e < NE; e++) { p[e] = expf(logit[e] - mx); sum += p[e]; }
    float inv = 1.f / sum;
    int e0 = 0, e1 = -1; float p0 = -1.f, p1 = -1.f;
#pragma unroll
    for (int e = 0; e < NE; e++) {
      float pe = p[e] * inv;
      if (pe > p0) { p1 = p0; e1 = e0; p0 = pe; e0 = e; }
      else if (pe > p1) { p1 = pe; e1 = e; }
    }
    // renormalize: softmax over the two probabilities (as in reference)
    float q0 = expf(p0), q1 = expf(p1);
    float qs = q0 + q1;
    float w0 = q0 / qs, w1 = q1 / qs;
    int pos0 = atomicAdd(&cnt[e0], 1);
    lists[e0 * T_TOK + pos0] = t * 2;
    int pos1 = atomicAdd(&cnt[e1], 1);
    lists[e1 * T_TOK + pos1] = t * 2 + 1;
    wpair[t * 2] = w0; wpair[t * 2 + 1] = w1;
  }
}

// ---------------- fused gate+up GEMM, 128x128 tile, epilogue silu(g)*u -> bf16 H ----------------
// A = Xbf [rows, DM] bf16 (rows gathered for experts), B = Wg/Wu [DF, DM] fp32 (K-contig)
template <bool GATHER>
__global__ __launch_bounds__(256, 2) void gateup_kernel(
    const unsigned short* __restrict__ Xbf,
    const float* __restrict__ Wg_all, const float* __restrict__ Wu_all,
    unsigned short* __restrict__ H,
    const int* __restrict__ lists, const int* __restrict__ cnt) {
  int e = blockIdx.z;
  int M = GATHER ? cnt[e] : T_TOK;
  int m0 = blockIdx.x * 128;
  if (m0 >= M) return;
  int n0 = blockIdx.y * 128;
  const float* Wg = Wg_all + (GATHER ? (size_t)e * DF * DM : 0);
  const float* Wu = Wu_all + (GATHER ? (size_t)e * DF * DM : 0);

  __shared__ alignas(16) unsigned short As[128 * 32];
  __shared__ alignas(16) unsigned short Bg[128 * 32];
  __shared__ alignas(16) unsigned short Bu[128 * 32];
  __shared__ int sp[128];

  int tid = threadIdx.x;
  if (tid < 128) {
    int i = m0 + tid;
    sp[tid] = GATHER ? lists[e * T_TOK + min(i, M - 1)] : i;
  }
  __syncthreads();

  // A staging: chunk c = it*256+tid covers row=c/4, k=(c%4)*8 (16B)
  int rA0 = tid >> 2, rA1 = 64 + (tid >> 2), kkA = (tid & 3) * 8;
  int x0 = GATHER ? (sp[rA0] >> 1) : sp[rA0];
  int x1 = GATHER ? (sp[rA1] >> 1) : sp[rA1];
  const unsigned short* a0 = Xbf + (size_t)x0 * DM;
  const unsigned short* a1 = Xbf + (size_t)x1 * DM;
  // B staging: row = tid/2, kk = (tid&1)*16 (16 floats -> 16 bf16)
  int rB = tid >> 1, kkB = (tid & 1) * 16;
  const float* bgp = Wg + (size_t)(n0 + rB) * DM;
  const float* bup = Wu + (size_t)(n0 + rB) * DM;

  int lane = tid & 63, wv = tid >> 6;
  int wm = (wv >> 1) * 64, wn = (wv & 1) * 64;
  int quad = lane >> 4, l16 = lane & 15;

  f32x4 accg[4][4], accu[4][4];
  f32x4 zero = {0.f, 0.f, 0.f, 0.f};
#pragma unroll
  for (int i = 0; i < 4; i++)
#pragma unroll
    for (int j = 0; j < 4; j++) { accg[i][j] = zero; accu[i][j] = zero; }

  for (int k0 = 0; k0 < DM; k0 += 32) {
    uint4 av0 = *(const uint4*)(a0 + k0 + kkA);
    uint4 av1 = *(const uint4*)(a1 + k0 + kkA);
    float4 g0 = *(const float4*)(bgp + k0 + kkB);
    float4 g1 = *(const float4*)(bgp + k0 + kkB + 4);
    float4 g2 = *(const float4*)(bgp + k0 + kkB + 8);
    float4 g3 = *(const float4*)(bgp + k0 + kkB + 12);
    float4 u0 = *(const float4*)(bup + k0 + kkB);
    float4 u1 = *(const float4*)(bup + k0 + kkB + 4);
    float4 u2 = *(const float4*)(bup + k0 + kkB + 8);
    float4 u3 = *(const float4*)(bup + k0 + kkB + 12);
    __syncthreads();
    *(uint4*)&As[rA0 * 32 + kkA] = av0;
    *(uint4*)&As[rA1 * 32 + kkA] = av1;
    *(uint4*)&Bg[rB * 32 + kkB] = pack8(g0, g1);
    *(uint4*)&Bg[rB * 32 + kkB + 8] = pack8(g2, g3);
    *(uint4*)&Bu[rB * 32 + kkB] = pack8(u0, u1);
    *(uint4*)&Bu[rB * 32 + kkB + 8] = pack8(u2, u3);
    __syncthreads();
    bf16x8 af[4], bgf[4], buf_[4];
#pragma unroll
    for (int mi = 0; mi < 4; mi++)
      af[mi] = *(const bf16x8*)&As[(wm + mi * 16 + l16) * 32 + quad * 8];
#pragma unroll
    for (int ni = 0; ni < 4; ni++) {
      bgf[ni] = *(const bf16x8*)&Bg[(wn + ni * 16 + l16) * 32 + quad * 8];
      buf_[ni] = *(const bf16x8*)&Bu[(wn + ni * 16 + l16) * 32 + quad * 8];
    }
#pragma unroll
    for (int mi = 0; mi < 4; mi++)
#pragma unroll
      for (int ni = 0; ni < 4; ni++) {
        accg[mi][ni] = __builtin_amdgcn_mfma_f32_16x16x32_bf16(af[mi], bgf[ni], accg[mi][ni], 0, 0, 0);
        accu[mi][ni] = __builtin_amdgcn_mfma_f32_16x16x32_bf16(af[mi], buf_[ni], accu[mi][ni], 0, 0, 0);
      }
  }

  // epilogue: h = silu(g)*u, bf16 store. D layout: row=quad*4+r, col=l16
#pragma unroll
  for (int mi = 0; mi < 4; mi++)
#pragma unroll
    for (int ni = 0; ni < 4; ni++)
#pragma unroll
      for (int r = 0; r < 4; r++) {
        int row = wm + mi * 16 + quad * 4 + r;
        if (m0 + row < M) {
          int hr = sp[row];  // pair id (GATHER) or dense row
          int col = wn + ni * 16 + l16;
          float g = accg[mi][ni][r], u = accu[mi][ni][r];
          float h = (g / (1.f + __expf(-g))) * u;
          H[(size_t)hr * DF + n0 + col] = f2bf(h);
        }
      }
}

// ---------------- down GEMM: A = H [rows, DF] bf16, B = Wd [DM, DF] fp32 ----------------
template <bool GATHER>
__global__ __launch_bounds__(256, 2) void down_kernel(
    const unsigned short* __restrict__ Hbase, const float* __restrict__ Wd_all,
    float* __restrict__ out,
    const int* __restrict__ lists, const int* __restrict__ cnt,
    const float* __restrict__ wpair) {
  int e = blockIdx.z;
  int M = GATHER ? cnt[e] : T_TOK;
  int m0 = blockIdx.x * 128;
  if (m0 >= M) return;
  int n0 = blockIdx.y * 128;
  const float* Wd = Wd_all + (GATHER ? (size_t)e * DM * DF : 0);

  __shared__ alignas(16) unsigned short As[128 * 32];
  __shared__ alignas(16) unsigned short Bs[128 * 32];
  __shared__ int sp[128];
  __shared__ float sw[128];

  int tid = threadIdx.x;
  if (tid < 128) {
    int i = m0 + tid;
    if (GATHER) {
      int p = lists[e * T_TOK + min(i, M - 1)];
      sp[tid] = p;
      sw[tid] = wpair[p];
    } else {
      sp[tid] = i;
      sw[tid] = 1.f;
    }
  }
  __syncthreads();

  int rA0 = tid >> 2, rA1 = 64 + (tid >> 2), kkA = (tid & 3) * 8;
  const unsigned short* a0 = Hbase + (size_t)sp[rA0] * DF;
  const unsigned short* a1 = Hbase + (size_t)sp[rA1] * DF;
  int rB = tid >> 1, kkB = (tid & 1) * 16;
  const float* bwp = Wd + (size_t)(n0 + rB) * DF;

  int lane = tid & 63, wv = tid >> 6;
  int wm = (wv >> 1) * 64, wn = (wv & 1) * 64;
  int quad = lane >> 4, l16 = lane & 15;

  f32x4 acc[4][4];
  f32x4 zero = {0.f, 0.f, 0.f, 0.f};
#pragma unroll
  for (int i = 0; i < 4; i++)
#pragma unroll
    for (int j = 0; j < 4; j++) acc[i][j] = zero;

  for (int k0 = 0; k0 < DF; k0 += 32) {
    uint4 av0 = *(const uint4*)(a0 + k0 + kkA);
    uint4 av1 = *(const uint4*)(a1 + k0 + kkA);
    float4 b0 = *(const float4*)(bwp + k0 + kkB);
    float4 b1 = *(const float4*)(bwp + k0 + kkB + 4);
    float4 b2 = *(const float4*)(bwp + k0 + kkB + 8);
    float4 b3 = *(const float4*)(bwp + k0 + kkB + 12);
    __syncthreads();
    *(uint4*)&As[rA0 * 32 + kkA] = av0;
    *(uint4*)&As[rA1 * 32 + kkA] = av1;
    *(uint4*)&Bs[rB * 32 + kkB] = pack8(b0, b1);
    *(uint4*)&Bs[rB * 32 + kkB + 8] = pack8(b2, b3);
    __syncthreads();
    bf16x8 af[4], bf_[4];
#pragma unroll
    for (int mi = 0; mi < 4; mi++)
      af[mi] = *(const bf16x8*)&As[(wm + mi * 16 + l16) * 32 + quad * 8];
#pragma unroll
    for (int ni = 0; ni < 4; ni++)
      bf_[ni] = *(const bf16x8*)&Bs[(wn + ni * 16 + l16) * 32 + quad * 8];
#pragma unroll
    for (int mi = 0; mi < 4; mi++)
#pragma unroll
      for (int ni = 0; ni < 4; ni++)
        acc[mi][ni] = __builtin_amdgcn_mfma_f32_16x16x32_bf16(af[mi], bf_[ni], acc[mi][ni], 0, 0, 0);
  }

#pragma unroll
  for (int mi = 0; mi < 4; mi++)
#pragma unroll
    for (int ni = 0; ni < 4; ni++)
#pragma unroll
      for (int r = 0; r < 4; r++) {
        int row = wm + mi * 16 + quad * 4 + r;
        if (m0 + row < M) {
          int col = n0 + wn + ni * 16 + l16;
          float v = acc[mi][ni][r];
          if (GATHER) {
            int t = sp[row] >> 1;
            atomicAdd(&out[(size_t)t * DM + col], sw[row] * v);
          } else {
            out[(size_t)sp[row] * DM + col] = v;
          }
        }
      }
}

extern "C" void kernel_launch(void* const* d_in, const int* in_sizes, int n_in,
                              void* d_out, int out_size, void* d_ws, size_t ws_size,
                              hipStream_t stream) {
  const float* X       = (const float*)d_in[0];
  const float* RW      = (const float*)d_in[1];
  const float* bias    = (const float*)d_in[2];
  const float* sw_gate = (const float*)d_in[3];
  const float* sw_up   = (const float*)d_in[4];
  const float* sw_down = (const float*)d_in[5];
  const float* ew_gate = (const float*)d_in[6];
  const float* ew_up   = (const float*)d_in[7];
  const float* ew_down = (const float*)d_in[8];
  float* out = (float*)d_out;

  char* ws = (char*)d_ws;
  unsigned short* Xbf   = (unsigned short*)ws;                              // 8 MB
  unsigned short* Hsh   = (unsigned short*)(ws + ((size_t)8 << 20));        // 16 MB
  unsigned short* Hpair = (unsigned short*)(ws + ((size_t)24 << 20));       // 32 MB
  int*   lists = (int*)(ws + ((size_t)56 << 20));                           // 128 KB
  float* wpair = (float*)(ws + ((size_t)56 << 20) + (128 << 10));           // 32 KB
  int*   cnt   = (int*)(ws + ((size_t)56 << 20) + (160 << 10));             // 32 B

  hipMemsetAsync(cnt, 0, NE * sizeof(int), stream);
  cvt_x_kernel<<<T_TOK * DM / 4 / 256, 256, 0, stream>>>(X, Xbf);
  router_kernel<<<T_TOK / 4, 256, 0, stream>>>(X, RW, bias, cnt, lists, wpair);
  gateup_kernel<false><<<dim3(T_TOK / 128, DF / 128, 1), 256, 0, stream>>>(
      Xbf, sw_gate, sw_up, Hsh, lists, cnt);
  gateup_kernel<true><<<dim3(T_TOK / 128, DF / 128, NE), 256, 0, stream>>>(
      Xbf, ew_gate, ew_up, Hpair, lists, cnt);
  down_kernel<false><<<dim3(T_TOK / 128, DM / 128, 1), 256, 0, stream>>>(
      Hsh, sw_down, out, lists, cnt, wpair);
  down_kernel<true><<<dim3(T_TOK / 128, DM / 128, NE), 256, 0, stream>>>(
      Hpair, ew_down, out, lists, cnt, wpair);
}

// Round 2
// 903.645 us; speedup vs baseline: 1.3885x; 1.3885x over previous
//
#include <hip/hip_runtime.h>
#include <hip/hip_bf16.h>

#define T_TOK 4096
#define DM 1024
#define DF 2048
#define NE 8

typedef __attribute__((ext_vector_type(8))) short bf16x8;
typedef __attribute__((ext_vector_type(4))) float f32x4;

__device__ __forceinline__ unsigned short f2bf(float f) {
  union { float f; unsigned int i; } v; v.f = f;
  unsigned int r = v.i + 0x7fffu + ((v.i >> 16) & 1u);
  return (unsigned short)(r >> 16);
}

__device__ __forceinline__ float bf2f(unsigned short u) {
  union { unsigned int i; float f; } v; v.i = ((unsigned int)u) << 16;
  return v.f;
}

__device__ __forceinline__ uint4 pack8(float4 a, float4 b) {
  uint4 r;
  r.x = (unsigned int)f2bf(a.x) | ((unsigned int)f2bf(a.y) << 16);
  r.y = (unsigned int)f2bf(a.z) | ((unsigned int)f2bf(a.w) << 16);
  r.z = (unsigned int)f2bf(b.x) | ((unsigned int)f2bf(b.y) << 16);
  r.w = (unsigned int)f2bf(b.z) | ((unsigned int)f2bf(b.w) << 16);
  return r;
}

// async global->LDS, 16B per lane; LDS dest is wave-uniform base + lane*16
__device__ __forceinline__ void gl2lds(const unsigned short* g, unsigned short* l) {
  __builtin_amdgcn_global_load_lds(
      (const __attribute__((address_space(1))) unsigned int*)g,
      (__attribute__((address_space(3))) unsigned int*)l, 16, 0, 0);
}

// ---------------- fused fp32 -> bf16 conversion for X + all 6 weight tensors ----------------
// 8 elements per thread, 2048 elements per block. Segment block ranges hardcoded.
__global__ void cvt_all_kernel(const float* __restrict__ X,
                               const float* __restrict__ swg, const float* __restrict__ swu,
                               const float* __restrict__ swd,
                               const float* __restrict__ ewg, const float* __restrict__ ewu,
                               const float* __restrict__ ewd,
                               unsigned short* __restrict__ Xbf,
                               unsigned short* __restrict__ Wg_sh, unsigned short* __restrict__ Wu_sh,
                               unsigned short* __restrict__ Wd_sh,
                               unsigned short* __restrict__ Wg_ex, unsigned short* __restrict__ Wu_ex,
                               unsigned short* __restrict__ Wd_ex) {
  int b = blockIdx.x;
  const float* src; unsigned short* dst; int base;
  if (b < 2048)        { src = X;   dst = Xbf;   base = 0; }
  else if (b < 3072)   { src = swg; dst = Wg_sh; base = 2048; }
  else if (b < 4096)   { src = swu; dst = Wu_sh; base = 3072; }
  else if (b < 5120)   { src = swd; dst = Wd_sh; base = 4096; }
  else if (b < 13312)  { src = ewg; dst = Wg_ex; base = 5120; }
  else if (b < 21504)  { src = ewu; dst = Wu_ex; base = 13312; }
  else                 { src = ewd; dst = Wd_ex; base = 21504; }
  size_t idx = (size_t)(b - base) * 256 + threadIdx.x;  // 8-elt chunk index
  float4 a = ((const float4*)src)[2 * idx];
  float4 c = ((const float4*)src)[2 * idx + 1];
  ((uint4*)dst)[idx] = pack8(a, c);
}

// ---------------- router: logits -> softmax -> top2 -> softmax(top2 probs) ----------------
__global__ void router_kernel(const float* __restrict__ X, const float* __restrict__ RW,
                              const float* __restrict__ bias, int* __restrict__ cnt,
                              int* __restrict__ lists, float* __restrict__ wpair) {
  int t = blockIdx.x * 4 + (threadIdx.x >> 6);   // one wave per token
  int lane = threadIdx.x & 63;
  float xv[16];
#pragma unroll
  for (int j = 0; j < 16; j++) xv[j] = X[(size_t)t * DM + lane + 64 * j];
  float logit[NE];
#pragma unroll
  for (int e = 0; e < NE; e++) {
    float s = 0.f;
#pragma unroll
    for (int j = 0; j < 16; j++) s += xv[j] * RW[e * DM + lane + 64 * j];
#pragma unroll
    for (int off = 32; off > 0; off >>= 1) s += __shfl_xor(s, off);
    logit[e] = s + bias[e];
  }
  if (lane == 0) {
    float mx = logit[0];
#pragma unroll
    for (int e = 1; e < NE; e++) mx = fmaxf(mx, logit[e]);
    float p[NE]; float sum = 0.f;
#pragma unroll
    for (int e = 0; e < NE; e++) { p[e] = expf(logit[e] - mx); sum += p[e]; }
    float inv = 1.f / sum;
    int e0 = 0, e1 = -1; float p0 = -1.f, p1 = -1.f;
#pragma unroll
    for (int e = 0; e < NE; e++) {
      float pe = p[e] * inv;
      if (pe > p0) { p1 = p0; e1 = e0; p0 = pe; e0 = e; }
      else if (pe > p1) { p1 = pe; e1 = e; }
    }
    float q0 = expf(p0), q1 = expf(p1);
    float qs = q0 + q1;
    wpair[t * 2] = q0 / qs; wpair[t * 2 + 1] = q1 / qs;
    int pos0 = atomicAdd(&cnt[e0], 1);
    lists[e0 * T_TOK + pos0] = t * 2;
    int pos1 = atomicAdd(&cnt[e1], 1);
    lists[e1 * T_TOK + pos1] = t * 2 + 1;
  }
}

// ---------------- fused gate+up GEMM (m97 structure), epilogue silu(g)*u -> bf16 H --------
// A = Xbf [tok, DM] bf16 (GATHER: rows via lists), B = Wg/Wu [DF, DM] bf16
template <bool GATHER>
__global__ __launch_bounds__(256, 2) void gateup_kernel(
    const unsigned short* __restrict__ Xbf,
    const unsigned short* __restrict__ Wg_all, const unsigned short* __restrict__ Wu_all,
    unsigned short* __restrict__ H,
    const int* __restrict__ lists, const int* __restrict__ cnt) {
  int e = blockIdx.z;
  int M = GATHER ? cnt[e] : T_TOK;
  int m0 = blockIdx.x * 128;
  if (m0 >= M) return;
  int n0 = blockIdx.y * 128;
  const unsigned short* Wg = Wg_all + (GATHER ? (size_t)e * DF * DM : 0);
  const unsigned short* Wu = Wu_all + (GATHER ? (size_t)e * DF * DM : 0);

  __shared__ alignas(16) unsigned short As[128 * 32];
  __shared__ alignas(16) unsigned short Bg[128 * 32];
  __shared__ alignas(16) unsigned short Bu[128 * 32];
  __shared__ int sp[128];

  int tid = threadIdx.x;
  if (tid < 128) {
    int i = m0 + tid;
    sp[tid] = GATHER ? lists[e * T_TOK + min(i, M - 1)] : i;
  }
  __syncthreads();

  int lane = tid & 63, wv = tid >> 6;
  // DMA staging: wave wv owns regions 2wv, 2wv+1; region r = rows [16r,16r+16), 1024 B of LDS
  int r0 = 2 * wv, r1 = r0 + 1;
  int rowS0 = r0 * 16 + (lane >> 2), rowS1 = r1 * 16 + (lane >> 2);
  int kk = (lane & 3) * 8;
  int xr0 = GATHER ? (sp[rowS0] >> 1) : sp[rowS0];
  int xr1 = GATHER ? (sp[rowS1] >> 1) : sp[rowS1];
  const unsigned short* gA0 = Xbf + (size_t)xr0 * DM + kk;
  const unsigned short* gA1 = Xbf + (size_t)xr1 * DM + kk;
  const unsigned short* gG0 = Wg + (size_t)(n0 + rowS0) * DM + kk;
  const unsigned short* gG1 = Wg + (size_t)(n0 + rowS1) * DM + kk;
  const unsigned short* gU0 = Wu + (size_t)(n0 + rowS0) * DM + kk;
  const unsigned short* gU1 = Wu + (size_t)(n0 + rowS1) * DM + kk;
  unsigned short* lA0 = &As[r0 * 512]; unsigned short* lA1 = &As[r1 * 512];
  unsigned short* lG0 = &Bg[r0 * 512]; unsigned short* lG1 = &Bg[r1 * 512];
  unsigned short* lU0 = &Bu[r0 * 512]; unsigned short* lU1 = &Bu[r1 * 512];

  int wm = (wv >> 1) * 64, wn = (wv & 1) * 64;
  int quad = lane >> 4, l16 = lane & 15;

  f32x4 accg[4][4], accu[4][4];
  f32x4 zero = {0.f, 0.f, 0.f, 0.f};
#pragma unroll
  for (int i = 0; i < 4; i++)
#pragma unroll
    for (int j = 0; j < 4; j++) { accg[i][j] = zero; accu[i][j] = zero; }

  for (int k0 = 0; k0 < DM; k0 += 32) {
    __syncthreads();
    gl2lds(gA0 + k0, lA0);
    gl2lds(gA1 + k0, lA1);
    gl2lds(gG0 + k0, lG0);
    gl2lds(gG1 + k0, lG1);
    gl2lds(gU0 + k0, lU0);
    gl2lds(gU1 + k0, lU1);
    __syncthreads();
    bf16x8 af[4], bgf[4], buf_[4];
#pragma unroll
    for (int mi = 0; mi < 4; mi++)
      af[mi] = *(const bf16x8*)&As[(wm + mi * 16 + l16) * 32 + quad * 8];
#pragma unroll
    for (int ni = 0; ni < 4; ni++) {
      bgf[ni] = *(const bf16x8*)&Bg[(wn + ni * 16 + l16) * 32 + quad * 8];
      buf_[ni] = *(const bf16x8*)&Bu[(wn + ni * 16 + l16) * 32 + quad * 8];
    }
#pragma unroll
    for (int mi = 0; mi < 4; mi++)
#pragma unroll
      for (int ni = 0; ni < 4; ni++) {
        accg[mi][ni] = __builtin_amdgcn_mfma_f32_16x16x32_bf16(af[mi], bgf[ni], accg[mi][ni], 0, 0, 0);
        accu[mi][ni] = __builtin_amdgcn_mfma_f32_16x16x32_bf16(af[mi], buf_[ni], accu[mi][ni], 0, 0, 0);
      }
  }

  // epilogue: h = silu(g)*u -> bf16. D layout: row=quad*4+r, col=l16
#pragma unroll
  for (int mi = 0; mi < 4; mi++)
#pragma unroll
    for (int ni = 0; ni < 4; ni++)
#pragma unroll
      for (int r = 0; r < 4; r++) {
        int row = wm + mi * 16 + quad * 4 + r;
        if (m0 + row < M) {
          int hr = sp[row];  // pair id (GATHER) or dense token row
          int col = wn + ni * 16 + l16;
          float g = accg[mi][ni][r], u = accu[mi][ni][r];
          float h = (g / (1.f + __expf(-g))) * u;
          H[(size_t)hr * DF + n0 + col] = f2bf(h);
        }
      }
}

// ---------------- down GEMM: A = H [rows, DF] bf16, B = Wd [DM, DF] bf16 ----------------
// GATHER: store raw expert output to Opair (bf16); else: store fp32 to out.
template <bool GATHER>
__global__ __launch_bounds__(256, 2) void down_kernel(
    const unsigned short* __restrict__ Hbase, const unsigned short* __restrict__ Wd_all,
    float* __restrict__ out, unsigned short* __restrict__ Opair,
    const int* __restrict__ lists, const int* __restrict__ cnt) {
  int e = blockIdx.z;
  int M = GATHER ? cnt[e] : T_TOK;
  int m0 = blockIdx.x * 128;
  if (m0 >= M) return;
  int n0 = blockIdx.y * 128;
  const unsigned short* Wd = Wd_all + (GATHER ? (size_t)e * DM * DF : 0);

  __shared__ alignas(16) unsigned short As[128 * 32];
  __shared__ alignas(16) unsigned short Bs[128 * 32];
  __shared__ int sp[128];

  int tid = threadIdx.x;
  if (tid < 128) {
    int i = m0 + tid;
    sp[tid] = GATHER ? lists[e * T_TOK + min(i, M - 1)] : i;
  }
  __syncthreads();

  int lane = tid & 63, wv = tid >> 6;
  int r0 = 2 * wv, r1 = r0 + 1;
  int rowS0 = r0 * 16 + (lane >> 2), rowS1 = r1 * 16 + (lane >> 2);
  int kk = (lane & 3) * 8;
  const unsigned short* gA0 = Hbase + (size_t)sp[rowS0] * DF + kk;
  const unsigned short* gA1 = Hbase + (size_t)sp[rowS1] * DF + kk;
  const unsigned short* gB0 = Wd + (size_t)(n0 + rowS0) * DF + kk;
  const unsigned short* gB1 = Wd + (size_t)(n0 + rowS1) * DF + kk;
  unsigned short* lA0 = &As[r0 * 512]; unsigned short* lA1 = &As[r1 * 512];
  unsigned short* lB0 = &Bs[r0 * 512]; unsigned short* lB1 = &Bs[r1 * 512];

  int wm = (wv >> 1) * 64, wn = (wv & 1) * 64;
  int quad = lane >> 4, l16 = lane & 15;

  f32x4 acc[4][4];
  f32x4 zero = {0.f, 0.f, 0.f, 0.f};
#pragma unroll
  for (int i = 0; i < 4; i++)
#pragma unroll
    for (int j = 0; j < 4; j++) acc[i][j] = zero;

  for (int k0 = 0; k0 < DF; k0 += 32) {
    __syncthreads();
    gl2lds(gA0 + k0, lA0);
    gl2lds(gA1 + k0, lA1);
    gl2lds(gB0 + k0, lB0);
    gl2lds(gB1 + k0, lB1);
    __syncthreads();
    bf16x8 af[4], bf_[4];
#pragma unroll
    for (int mi = 0; mi < 4; mi++)
      af[mi] = *(const bf16x8*)&As[(wm + mi * 16 + l16) * 32 + quad * 8];
#pragma unroll
    for (int ni = 0; ni < 4; ni++)
      bf_[ni] = *(const bf16x8*)&Bs[(wn + ni * 16 + l16) * 32 + quad * 8];
#pragma unroll
    for (int mi = 0; mi < 4; mi++)
#pragma unroll
      for (int ni = 0; ni < 4; ni++)
        acc[mi][ni] = __builtin_amdgcn_mfma_f32_16x16x32_bf16(af[mi], bf_[ni], acc[mi][ni], 0, 0, 0);
  }

#pragma unroll
  for (int mi = 0; mi < 4; mi++)
#pragma unroll
    for (int ni = 0; ni < 4; ni++)
#pragma unroll
      for (int r = 0; r < 4; r++) {
        int row = wm + mi * 16 + quad * 4 + r;
        if (m0 + row < M) {
          int col = n0 + wn + ni * 16 + l16;
          float v = acc[mi][ni][r];
          if (GATHER) {
            Opair[(size_t)sp[row] * DM + col] = f2bf(v);
          } else {
            out[(size_t)sp[row] * DM + col] = v;
          }
        }
      }
}

// ---------------- combine: out[t] += w0*Opair[2t] + w1*Opair[2t+1] ----------------
__global__ void combine_kernel(float* __restrict__ out, const unsigned short* __restrict__ Opair,
                               const float* __restrict__ wpair) {
  int idx = blockIdx.x * 256 + threadIdx.x;  // 8-element chunk
  int t = idx / (DM / 8);
  int c = (idx % (DM / 8)) * 8;
  float w0 = wpair[2 * t], w1 = wpair[2 * t + 1];
  const uint4* o0 = (const uint4*)(Opair + (size_t)(2 * t) * DM + c);
  const uint4* o1 = (const uint4*)(Opair + (size_t)(2 * t + 1) * DM + c);
  float4* op = (float4*)(out + (size_t)t * DM + c);
  uint4 a = o0[0], b = o1[0];
  float4 x0 = op[0], x1 = op[1];
  uint4 a2 = ((const uint4*)o0)[1], b2 = ((const uint4*)o1)[1];
  x0.x += w0 * bf2f(a.x & 0xffff)  + w1 * bf2f(b.x & 0xffff);
  x0.y += w0 * bf2f(a.x >> 16)     + w1 * bf2f(b.x >> 16);
  x0.z += w0 * bf2f(a.y & 0xffff)  + w1 * bf2f(b.y & 0xffff);
  x0.w += w0 * bf2f(a.y >> 16)     + w1 * bf2f(b.y >> 16);
  x1.x += w0 * bf2f(a.z & 0xffff)  + w1 * bf2f(b.z & 0xffff);
  x1.y += w0 * bf2f(a.z >> 16)     + w1 * bf2f(b.z >> 16);
  x1.z += w0 * bf2f(a.w & 0xffff)  + w1 * bf2f(b.w & 0xffff);
  x1.w += w0 * bf2f(a.w >> 16)     + w1 * bf2f(b.w >> 16);
  op[0] = x0; op[1] = x1;
  (void)a2; (void)b2;
}

extern "C" void kernel_launch(void* const* d_in, const int* in_sizes, int n_in,
                              void* d_out, int out_size, void* d_ws, size_t ws_size,
                              hipStream_t stream) {
  const float* X       = (const float*)d_in[0];
  const float* RW      = (const float*)d_in[1];
  const float* bias    = (const float*)d_in[2];
  const float* sw_gate = (const float*)d_in[3];
  const float* sw_up   = (const float*)d_in[4];
  const float* sw_down = (const float*)d_in[5];
  const float* ew_gate = (const float*)d_in[6];
  const float* ew_up   = (const float*)d_in[7];
  const float* ew_down = (const float*)d_in[8];
  float* out = (float*)d_out;

  char* ws = (char*)d_ws;
  const size_t MB = 1 << 20;
  unsigned short* Xbf   = (unsigned short*)(ws);              //   8 MB
  unsigned short* Hsh   = (unsigned short*)(ws + 8 * MB);     //  16 MB
  unsigned short* Hpair = (unsigned short*)(ws + 24 * MB);    //  32 MB
  unsigned short* Wg_sh = (unsigned short*)(ws + 56 * MB);    //   4 MB
  unsigned short* Wu_sh = (unsigned short*)(ws + 60 * MB);    //   4 MB
  unsigned short* Wd_sh = (unsigned short*)(ws + 64 * MB);    //   4 MB
  unsigned short* Wg_ex = (unsigned short*)(ws + 68 * MB);    //  32 MB
  unsigned short* Wu_ex = (unsigned short*)(ws + 100 * MB);   //  32 MB
  unsigned short* Wd_ex = (unsigned short*)(ws + 132 * MB);   //  32 MB
  unsigned short* Opair = (unsigned short*)(ws + 164 * MB);   //  16 MB
  int*   lists = (int*)(ws + 180 * MB);                       // 128 KB
  float* wpair = (float*)(ws + 180 * MB + (128 << 10));       //  32 KB
  int*   cnt   = (int*)(ws + 180 * MB + (160 << 10));         //  32 B

  hipMemsetAsync(cnt, 0, NE * sizeof(int), stream);
  cvt_all_kernel<<<29696, 256, 0, stream>>>(X, sw_gate, sw_up, sw_down, ew_gate, ew_up, ew_down,
                                            Xbf, Wg_sh, Wu_sh, Wd_sh, Wg_ex, Wu_ex, Wd_ex);
  router_kernel<<<T_TOK / 4, 256, 0, stream>>>(X, RW, bias, cnt, lists, wpair);
  gateup_kernel<false><<<dim3(T_TOK / 128, DF / 128, 1), 256, 0, stream>>>(
      Xbf, Wg_sh, Wu_sh, Hsh, lists, cnt);
  gateup_kernel<true><<<dim3(T_TOK / 128, DF / 128, NE), 256, 0, stream>>>(
      Xbf, Wg_ex, Wu_ex, Hpair, lists, cnt);
  down_kernel<false><<<dim3(T_TOK / 128, DM / 128, 1), 256, 0, stream>>>(
      Hsh, Wd_sh, out, Opair, lists, cnt);
  down_kernel<true><<<dim3(T_TOK / 128, DM / 128, NE), 256, 0, stream>>>(
      Hpair, Wd_ex, out, Opair, lists, cnt);
  combine_kernel<<<T_TOK * DM / 8 / 256, 256, 0, stream>>>(out, Opair, wpair);
}